// Round 1
// baseline (33.707 us; speedup 1.0000x reference)
//
#include <hip/hip_runtime.h>
#include <hip/hip_bf16.h>

// Problem constants (from reference)
constexpr int T = 2048;
constexpr int B = 8;
constexpr int C = 1024;
constexpr int H = 16;
constexpr int K = 31;
constexpr int G = C / H;       // 64 channels per head
constexpr int BC = B * C;      // 8192 (b,c) columns; stride between time steps

// Tiling
constexpr int TT = 128;        // time steps per thread
constexpr int U = 8;           // outputs per inner iteration
constexpr int NB = K - 1 + U;  // sliding register window size = 38
constexpr int BLOCK = 256;
constexpr int BLK_PER_CHUNK = BC / BLOCK;   // 32
constexpr int NCHUNK = T / TT;              // 16
constexpr int NBLK = BLK_PER_CHUNK * NCHUNK; // 512

// ---------------------------------------------------------------------------
// Kernel 1: per-head softmax of weights -> d_ws (H*K floats)
// ---------------------------------------------------------------------------
__global__ void softmax_w_kernel(const float* __restrict__ w, float* __restrict__ wsm) {
    int h = threadIdx.x;
    if (h >= H) return;
    float m = -1e30f;
    #pragma unroll
    for (int k = 0; k < K; ++k) m = fmaxf(m, w[h * K + k]);
    float e[K];
    float s = 0.0f;
    #pragma unroll
    for (int k = 0; k < K; ++k) {
        e[k] = expf(w[h * K + k] - m);
        s += e[k];
    }
    float inv = 1.0f / s;
    #pragma unroll
    for (int k = 0; k < K; ++k) wsm[h * K + k] = e[k] * inv;
}

// ---------------------------------------------------------------------------
// Kernel 2: causal depthwise conv along T with sliding register window.
// out[t,b,c] = sum_{d=0..K-1} wr[d] * x[t-d, b, c] + bias[c],  wr[d] = w[h][K-1-d]
// ---------------------------------------------------------------------------
__global__ __launch_bounds__(BLOCK) void lconv_tbc_kernel(
        const float* __restrict__ x,
        const float* __restrict__ wsm,
        const float* __restrict__ bias,
        float* __restrict__ out) {
    const int tid = threadIdx.x;
    const int cb = blockIdx.x % BLK_PER_CHUNK;         // which bc slice
    const int chunk = blockIdx.x / BLK_PER_CHUNK;      // which time chunk
    const int bc = cb * BLOCK + tid;                   // [0, BC)
    const int c = bc & (C - 1);
    // Each 64-lane wave spans exactly one head (c0 multiple of 64, G=64):
    const int h = __builtin_amdgcn_readfirstlane(c >> 6);

    const float bi = bias[c];

    // Reversed weights so out[t] = sum_d wr[d] * x[t-d]; wave-uniform -> SGPRs.
    float wr[K];
    #pragma unroll
    for (int d = 0; d < K; ++d) wr[d] = wsm[h * K + (K - 1 - d)];

    const int t0 = chunk * TT;
    const float* xp = x + (long long)t0 * BC + bc;
    float* op = out + (long long)t0 * BC + bc;

    // Sliding window: buf[j] = x[tbase - (K-1) + j]
    float buf[NB];
    if (chunk == 0) {
        #pragma unroll
        for (int j = 0; j < K - 1; ++j) buf[j] = 0.0f;
    } else {
        #pragma unroll
        for (int j = 0; j < K - 1; ++j)
            buf[j] = xp[(long long)(j - (K - 1)) * BC];
    }

    for (int it = 0; it < TT / U; ++it) {
        // Load U new time steps (coalesced across lanes; stride BC along T)
        #pragma unroll
        for (int u = 0; u < U; ++u)
            buf[K - 1 + u] = xp[(long long)u * BC];

        // Compute U outputs, all register indices compile-time constant
        #pragma unroll
        for (int u = 0; u < U; ++u) {
            float acc = bi;
            #pragma unroll
            for (int d = 0; d < K; ++d)
                acc += wr[d] * buf[K - 1 + u - d];
            op[(long long)u * BC] = acc;
        }

        // Shift window left by U (static indices)
        #pragma unroll
        for (int j = 0; j < K - 1; ++j) buf[j] = buf[j + U];

        xp += (long long)U * BC;
        op += (long long)U * BC;
    }
}

extern "C" void kernel_launch(void* const* d_in, const int* in_sizes, int n_in,
                              void* d_out, int out_size, void* d_ws, size_t ws_size,
                              hipStream_t stream) {
    const float* x = (const float*)d_in[0];      // [T, B, C]
    const float* w = (const float*)d_in[1];      // [H, 1, K]
    const float* bias = (const float*)d_in[2];   // [C]
    float* out = (float*)d_out;                  // [T, B, C]
    float* wsm = (float*)d_ws;                   // H*K floats scratch

    softmax_w_kernel<<<dim3(1), dim3(64), 0, stream>>>(w, wsm);
    lconv_tbc_kernel<<<dim3(NBLK), dim3(BLOCK), 0, stream>>>(x, wsm, bias, out);
}

// Round 2
// 33.541 us; speedup vs baseline: 1.0050x; 1.0050x over previous
//
#include <hip/hip_runtime.h>
#include <hip/hip_bf16.h>

// Problem constants (from reference)
constexpr int T = 2048;
constexpr int B = 8;
constexpr int C = 1024;
constexpr int H = 16;
constexpr int K = 31;
constexpr int BC = B * C;      // 8192 (b,c) columns; stride between time steps

// Tiling
constexpr int TT = 32;         // time steps per thread (small -> more blocks -> latency hiding)
constexpr int U = 8;           // outputs per inner iteration
constexpr int NB = K - 1 + U;  // sliding register window size = 38
constexpr int BLOCK = 256;
constexpr int BLK_PER_CHUNK = BC / BLOCK;    // 32
constexpr int NCHUNK = T / TT;               // 64
constexpr int NBLK = BLK_PER_CHUNK * NCHUNK; // 2048

// ---------------------------------------------------------------------------
// Causal depthwise conv along T with sliding register window.
// out[t,b,c] = sum_{d=0..K-1} wr[d] * x[t-d, b, c] + bias[c]
// wr[d] = softmax(w[h])[K-1-d], computed per-wave (head is wave-uniform).
// ---------------------------------------------------------------------------
__global__ __launch_bounds__(BLOCK) void lconv_tbc_kernel(
        const float* __restrict__ x,
        const float* __restrict__ w,
        const float* __restrict__ bias,
        float* __restrict__ out) {
    const int tid = threadIdx.x;
    const int cb = blockIdx.x % BLK_PER_CHUNK;         // which bc slice
    const int chunk = blockIdx.x / BLK_PER_CHUNK;      // which time chunk
    const int bc = cb * BLOCK + tid;                   // [0, BC)
    const int c = bc & (C - 1);
    // Each 64-lane wave spans exactly one head (c0 multiple of 64, G=64):
    const int h = __builtin_amdgcn_readfirstlane(c >> 6);

    const float bi = bias[c];

    // Per-wave softmax of this head's K taps (wave-uniform -> scalar loads).
    float wv[K];
    float m = -1e30f;
    #pragma unroll
    for (int k = 0; k < K; ++k) {
        wv[k] = w[h * K + k];
        m = fmaxf(m, wv[k]);
    }
    float s = 0.0f;
    #pragma unroll
    for (int k = 0; k < K; ++k) {
        wv[k] = __expf(wv[k] - m) ;
        s += wv[k];
    }
    const float inv = 1.0f / s;
    // Reversed weights so out[t] = sum_d wr[d] * x[t-d]
    float wr[K];
    #pragma unroll
    for (int d = 0; d < K; ++d) wr[d] = wv[K - 1 - d] * inv;

    const int t0 = chunk * TT;
    const float* xp = x + (long long)t0 * BC + bc;
    float* op = out + (long long)t0 * BC + bc;

    // Sliding window: buf[K-1+u] = x[t0+u]; buf[j<K-1] = history
    float buf[NB];
    if (chunk == 0) {
        #pragma unroll
        for (int j = 0; j < K - 1; ++j) buf[j] = 0.0f;
    } else {
        #pragma unroll
        for (int j = 0; j < K - 1; ++j)
            buf[j] = xp[(long long)(j - (K - 1)) * BC];
    }

    #pragma unroll
    for (int it = 0; it < TT / U; ++it) {
        // Load U new time steps (coalesced across lanes; stride BC along T)
        #pragma unroll
        for (int u = 0; u < U; ++u)
            buf[K - 1 + u] = xp[(long long)u * BC];

        // Compute U outputs, all register indices compile-time constant
        #pragma unroll
        for (int u = 0; u < U; ++u) {
            float acc = bi;
            #pragma unroll
            for (int d = 0; d < K; ++d)
                acc += wr[d] * buf[K - 1 + u - d];
            __builtin_nontemporal_store(acc, &op[(long long)u * BC]);
        }

        // Shift window left by U (static indices)
        #pragma unroll
        for (int j = 0; j < K - 1; ++j) buf[j] = buf[j + U];

        xp += (long long)U * BC;
        op += (long long)U * BC;
    }
}

extern "C" void kernel_launch(void* const* d_in, const int* in_sizes, int n_in,
                              void* d_out, int out_size, void* d_ws, size_t ws_size,
                              hipStream_t stream) {
    const float* x = (const float*)d_in[0];      // [T, B, C]
    const float* w = (const float*)d_in[1];      // [H, 1, K]
    const float* bias = (const float*)d_in[2];   // [C]
    float* out = (float*)d_out;                  // [T, B, C]

    lconv_tbc_kernel<<<dim3(NBLK), dim3(BLOCK), 0, stream>>>(x, w, bias, out);
}

// Round 3
// 29.966 us; speedup vs baseline: 1.1249x; 1.1193x over previous
//
#include <hip/hip_runtime.h>
#include <hip/hip_bf16.h>

// Problem constants (from reference)
constexpr int T = 2048;
constexpr int B = 8;
constexpr int C = 1024;
constexpr int H = 16;
constexpr int K = 31;
constexpr int BC = B * C;      // 8192 (b,c) columns; stride between time steps

// Tiling: whole chunk window in registers, one load batch per thread.
constexpr int TT = 32;               // outputs per thread
constexpr int NB = K - 1 + TT;       // 61 window registers
constexpr int BLOCK = 256;
constexpr int BLK_PER_CHUNK = BC / BLOCK;    // 32
constexpr int NCHUNK = T / TT;               // 64
constexpr int NBLK = BLK_PER_CHUNK * NCHUNK; // 2048

// ---------------------------------------------------------------------------
// out[t,b,c] = sum_{d=0..K-1} wr[d] * x[t-d, b, c] + bias[c]
// wr[d] = softmax(w[h])[K-1-d], wave-uniform -> SGPRs.
// ---------------------------------------------------------------------------
__global__ __launch_bounds__(BLOCK, 4) void lconv_tbc_kernel(
        const float* __restrict__ x,
        const float* __restrict__ w,
        const float* __restrict__ bias,
        float* __restrict__ out) {
    const int tid = threadIdx.x;
    const int cb = blockIdx.x & (BLK_PER_CHUNK - 1);   // bc slice
    const int chunk = blockIdx.x / BLK_PER_CHUNK;      // time chunk
    const int bc = cb * BLOCK + tid;                   // [0, BC)
    const int c = bc & (C - 1);
    // Each 64-lane wave spans exactly one head (c0 multiple of 64, G=64):
    const int h = __builtin_amdgcn_readfirstlane(c >> 6);

    // Per-wave softmax of this head's K taps.
    float wv[K];
    float m = -1e30f;
    #pragma unroll
    for (int k = 0; k < K; ++k) {
        wv[k] = w[h * K + k];
        m = fmaxf(m, wv[k]);
    }
    float s = 0.0f;
    #pragma unroll
    for (int k = 0; k < K; ++k) {
        wv[k] = __expf(wv[k] - m);
        s += wv[k];
    }
    const float inv = 1.0f / s;
    // Reversed weights, forced into SGPRs (wave-uniform value):
    float wr[K];
    #pragma unroll
    for (int d = 0; d < K; ++d)
        wr[d] = __uint_as_float(
            __builtin_amdgcn_readfirstlane(__float_as_uint(wv[K - 1 - d] * inv)));

    const float bi = bias[c];
    const int t0 = chunk * TT;
    const int base = t0 * BC + bc;   // element index; max ~16.8M fits int

    // Whole window in registers: buf[j] = x[t0 - (K-1) + j]
    float buf[NB];
    if (chunk == 0) {
        #pragma unroll
        for (int j = 0; j < K - 1; ++j) buf[j] = 0.0f;
    } else {
        #pragma unroll
        for (int j = 0; j < K - 1; ++j)
            buf[j] = x[base + (j - (K - 1)) * BC];
    }
    #pragma unroll
    for (int u = 0; u < TT; ++u)
        buf[K - 1 + u] = x[base + u * BC];

    // 32 outputs, 31 FMAs each, all register indices static.
    #pragma unroll
    for (int u = 0; u < TT; ++u) {
        float acc = bi;
        #pragma unroll
        for (int d = 0; d < K; ++d)
            acc = fmaf(wr[d], buf[K - 1 + u - d], acc);
        __builtin_nontemporal_store(acc, &out[base + u * BC]);
    }
}

extern "C" void kernel_launch(void* const* d_in, const int* in_sizes, int n_in,
                              void* d_out, int out_size, void* d_ws, size_t ws_size,
                              hipStream_t stream) {
    const float* x = (const float*)d_in[0];      // [T, B, C]
    const float* w = (const float*)d_in[1];      // [H, 1, K]
    const float* bias = (const float*)d_in[2];   // [C]
    float* out = (float*)d_out;                  // [T, B, C]

    lconv_tbc_kernel<<<dim3(NBLK), dim3(BLOCK), 0, stream>>>(x, w, bias, out);
}